// Round 2
// baseline (2392.228 us; speedup 1.0000x reference)
//
#include <hip/hip_runtime.h>
#include <math.h>

#define N 1024
#define SLOTS 16   // rows per lane: row r owned by lane (r & 63), slot (r >> 6)

// (v2,f2) beats (v1,f1): larger value wins; tie -> smaller flat index
__device__ __forceinline__ bool better(float v2, int f2, float v1, int f1) {
    return (v2 > v1) || (v2 == v1 && f2 < f1);
}

// ---------------------------------------------------------------------------
// Kernel 1: per-row argmax over all columns. One wave per row, coalesced.
// Also warms L2/L3 with the whole matrix for the greedy kernel's rebuilds.
// ---------------------------------------------------------------------------
__global__ __launch_bounds__(256) void init_rows(const float* __restrict__ C,
                                                 float* __restrict__ rowVal,
                                                 int* __restrict__ rowCol) {
    int row  = (blockIdx.x * blockDim.x + threadIdx.x) >> 6;
    int lane = threadIdx.x & 63;
    if (row >= N) return;
    const float* rp = C + (size_t)row * N;
    float best = -INFINITY;
    int bestc = 0;
    #pragma unroll
    for (int k = 0; k < N / 64; ++k) {
        int c = (k << 6) + lane;
        float v = rp[c];
        if (v > best) { best = v; bestc = c; }   // strict > keeps smallest col
    }
    #pragma unroll
    for (int m = 1; m < 64; m <<= 1) {
        float ov = __shfl_xor(best, m);
        int   oc = __shfl_xor(bestc, m);
        if (better(ov, oc, best, bestc)) { best = ov; bestc = oc; }
    }
    if (lane == 0) { rowVal[row] = best; rowCol[row] = bestc; }
}

// ---------------------------------------------------------------------------
// Kernel 2: the 1024 sequential greedy steps in ONE wave, all state in regs.
// No __syncthreads anywhere: wave-synchronous execution.
//   val[s], col[s]   : cached best over unused cols for row (s*64+lane)
//                      (val = -inf, col = -2 once the row is assigned)
//   maskbits bit k   : column (k*64 + lane) already used
// ---------------------------------------------------------------------------
__global__ __launch_bounds__(64) void greedy_wave(const float* __restrict__ C,
                                                  const float* __restrict__ rvIn,
                                                  const int* __restrict__ rcIn,
                                                  int* __restrict__ out,
                                                  int doInit) {
    const int lane = threadIdx.x;
    float val[SLOTS];
    int   col[SLOTS];
    unsigned maskbits = 0;

    if (!doInit) {
        #pragma unroll
        for (int s = 0; s < SLOTS; ++s) {
            val[s] = rvIn[(s << 6) + lane];
            col[s] = rcIn[(s << 6) + lane];
        }
    } else {
        // fallback (no workspace): wave-cooperative scan of every row
        #pragma unroll 1
        for (int r = 0; r < N; ++r) {
            const float* rp = C + (size_t)r * N;
            float best = -INFINITY; int bestc = N - 1;
            #pragma unroll
            for (int k = 0; k < SLOTS; ++k) {
                int c = (k << 6) + lane;
                float v = rp[c];
                if (v > best) { best = v; bestc = c; }
            }
            #pragma unroll
            for (int m = 1; m < 64; m <<= 1) {
                float ov = __shfl_xor(best, m);
                int   oc = __shfl_xor(bestc, m);
                if (better(ov, oc, best, bestc)) { best = ov; bestc = oc; }
            }
            if (lane == (r & 63)) {
                const int s = r >> 6;
                #pragma unroll
                for (int ss = 0; ss < SLOTS; ++ss)
                    if (ss == s) { val[ss] = best; col[ss] = bestc; }
            }
        }
    }

    #pragma unroll 1
    for (int iter = 0; iter < N; ++iter) {
        // ---- local argmax over this lane's 16 cached rows (register tree) --
        float tv[SLOTS]; int tf[SLOTS];
        #pragma unroll
        for (int s = 0; s < SLOTS; ++s) {
            tv[s] = val[s];
            tf[s] = ((((s << 6) + lane) << 10)) | (col[s] & (N - 1));
        }
        #pragma unroll
        for (int st = 1; st < SLOTS; st <<= 1) {
            #pragma unroll
            for (int s = 0; s < SLOTS; s += (st << 1)) {
                if (better(tv[s + st], tf[s + st], tv[s], tf[s])) {
                    tv[s] = tv[s + st]; tf[s] = tf[s + st];
                }
            }
        }
        // ---- 6-step butterfly: global argmax, result in all lanes ----------
        float bv = tv[0]; int bf = tf[0];
        #pragma unroll
        for (int m = 1; m < 64; m <<= 1) {
            float ov = __shfl_xor(bv, m);
            int   of = __shfl_xor(bf, m);
            if (better(ov, of, bv, bf)) { bv = ov; bf = of; }
        }
        const int br = bf >> 10;
        const int bc = bf & (N - 1);

        // ---- retire row br (owner lane), write its output column ----------
        if (lane == (br & 63)) {
            out[N + br] = bc;
            const int s = br >> 6;
            #pragma unroll
            for (int ss = 0; ss < SLOTS; ++ss)
                if (ss == s) { val[ss] = -INFINITY; col[ss] = -2; }
        }
        // ---- mark column bc used (owner lane's register bit) --------------
        if (lane == (bc & 63)) maskbits |= 1u << (bc >> 6);

        // ---- rows whose cached best column just died ----------------------
        unsigned inv = 0;
        #pragma unroll
        for (int s = 0; s < SLOTS; ++s)
            inv |= (col[s] == bc) ? (1u << s) : 0u;
        unsigned long long anyinv = __ballot(inv != 0);

        // ---- wave-cooperative rebuild of each invalidated row -------------
        while (anyinv) {
            const int srclane = __ffsll(anyinv) - 1;
            anyinv &= anyinv - 1;
            unsigned mbits = (unsigned)__shfl((int)inv, srclane);
            while (mbits) {
                const int s = __ffs(mbits) - 1;
                mbits &= mbits - 1;
                const int r = (s << 6) + srclane;
                const float* rp = C + (size_t)r * N;
                float best = -INFINITY; int bestc = N - 1;
                #pragma unroll
                for (int k = 0; k < SLOTS; ++k) {
                    int c = (k << 6) + lane;
                    float v = rp[c];
                    bool used = (maskbits >> k) & 1u;
                    if (!used && v > best) { best = v; bestc = c; }
                }
                #pragma unroll
                for (int mm = 1; mm < 64; mm <<= 1) {
                    float ov = __shfl_xor(best, mm);
                    int   oc = __shfl_xor(bestc, mm);
                    if (better(ov, oc, best, bestc)) { best = ov; bestc = oc; }
                }
                if (lane == srclane) {
                    #pragma unroll
                    for (int ss = 0; ss < SLOTS; ++ss)
                        if (ss == s) { val[ss] = best; col[ss] = bestc; }
                }
            }
        }
    }

    // ---- row-index half of the output: identity -------------------------
    #pragma unroll
    for (int s = 0; s < SLOTS; ++s) out[(s << 6) + lane] = (s << 6) + lane;
}

// ---------------------------------------------------------------------------
extern "C" void kernel_launch(void* const* d_in, const int* in_sizes, int n_in,
                              void* d_out, int out_size, void* d_ws, size_t ws_size,
                              hipStream_t stream) {
    const float* C = (const float*)d_in[0];
    int* out = (int*)d_out;

    if (ws_size >= (size_t)(N * 8)) {
        float* rv = (float*)d_ws;
        int*   rc = (int*)((char*)d_ws + (size_t)N * 4);
        init_rows<<<256, 256, 0, stream>>>(C, rv, rc);
        greedy_wave<<<1, 64, 0, stream>>>(C, rv, rc, out, 0);
    } else {
        greedy_wave<<<1, 64, 0, stream>>>(C, nullptr, nullptr, out, 1);
    }
}

// Round 3
// 1520.995 us; speedup vs baseline: 1.5728x; 1.5728x over previous
//
#include <hip/hip_runtime.h>
#include <math.h>

#define N 1024
#define SLOTS 16   // rows per lane: row r owned by lane (r & 63), slot (r >> 6)
#define K 8        // precomputed candidates per row

// (v2,f2) beats (v1,f1): larger value wins; tie -> smaller flat index
__device__ __forceinline__ bool better(float v2, int f2, float v1, int f1) {
    return (v2 > v1) || (v2 == v1 && f2 < f1);
}

// One reduce level via DPP (VALU latency, no DS pipe).
template<int CTRL>
__device__ __forceinline__ void dpp_step(float& v, int& f) {
    int ovi = __builtin_amdgcn_update_dpp(0, __float_as_int(v), CTRL, 0xF, 0xF, true);
    int ofi = __builtin_amdgcn_update_dpp(0, f, CTRL, 0xF, 0xF, true);
    float ov = __int_as_float(ovi);
    if (better(ov, ofi, v, f)) { v = ov; f = ofi; }
}

// Full-wave argmax on (v,f); result broadcast to all lanes.
// 4 DPP levels (within-16 uniform) + 4 group leaders via readlane + reg tree.
__device__ __forceinline__ void wave_argmax(float& v, int& f) {
    dpp_step<0xB1>(v, f);    // quad_perm [1,0,3,2]  (xor 1)
    dpp_step<0x4E>(v, f);    // quad_perm [2,3,0,1]  (xor 2)
    dpp_step<0x141>(v, f);   // row_half_mirror      (xor within 8)
    dpp_step<0x140>(v, f);   // row_mirror           (xor within 16)
    float v0 = __int_as_float(__builtin_amdgcn_readlane(__float_as_int(v), 0));
    int   f0 = __builtin_amdgcn_readlane(f, 0);
    float v1 = __int_as_float(__builtin_amdgcn_readlane(__float_as_int(v), 16));
    int   f1 = __builtin_amdgcn_readlane(f, 16);
    float v2 = __int_as_float(__builtin_amdgcn_readlane(__float_as_int(v), 32));
    int   f2 = __builtin_amdgcn_readlane(f, 32);
    float v3 = __int_as_float(__builtin_amdgcn_readlane(__float_as_int(v), 48));
    int   f3 = __builtin_amdgcn_readlane(f, 48);
    if (better(v1, f1, v0, f0)) { v0 = v1; f0 = f1; }
    if (better(v3, f3, v2, f2)) { v2 = v3; f2 = f3; }
    if (better(v2, f2, v0, f0)) { v0 = v2; f0 = f2; }
    v = v0; f = f0;
}

// ---------------------------------------------------------------------------
// Kernel 1: exact top-K per row by repeated argmax-with-exclusion.
// One wave per row; row cached in 16 VGPRs. Order = (val desc, col asc).
// Entry layout: .x = col, .y = float bits of value.
// ---------------------------------------------------------------------------
__global__ __launch_bounds__(256) void init_topk(const float* __restrict__ C,
                                                 uint2* __restrict__ wsList) {
    int row  = (blockIdx.x * blockDim.x + threadIdx.x) >> 6;
    int lane = threadIdx.x & 63;
    if (row >= N) return;
    const float* rp = C + (size_t)row * N;
    float rv[SLOTS];
    #pragma unroll
    for (int k = 0; k < SLOTS; ++k) rv[k] = rp[(k << 6) + lane];
    unsigned excl = 0;   // bit k: col (k*64+lane) already emitted
    for (int pass = 0; pass < K; ++pass) {
        float best = -INFINITY; int bc = N;
        #pragma unroll
        for (int k = 0; k < SLOTS; ++k) {
            int c = (k << 6) + lane;
            bool ex = (excl >> k) & 1u;
            if (!ex && rv[k] > best) { best = rv[k]; bc = c; }  // > keeps min col
        }
        wave_argmax(best, bc);
        if (lane == (bc & 63)) excl |= 1u << (bc >> 6);
        if (lane == 0) wsList[row * K + pass] = make_uint2((unsigned)bc, __float_as_uint(best));
    }
}

// ---------------------------------------------------------------------------
// Kernel 2: 1024 sequential greedy steps in ONE wave.
//   cache[r] (LDS): current best unused col of row r (.x=col, .y=valbits);
//                   col=0xFFFFFFFF + val=-inf once assigned.
//   list[r][j] (LDS): top-K candidates; ptrbits nibble s = list index of the
//                   cached entry for row (s*64+lane); 8 => list dead -> rescan.
//   colUsed (LDS bitset) for pop checks; maskbits (reg) for wave rescans.
// ---------------------------------------------------------------------------
__global__ __launch_bounds__(64) void greedy_wave(const float* __restrict__ C,
                                                  const uint2* __restrict__ wsList,
                                                  int* __restrict__ out,
                                                  int haveList) {
    __shared__ __align__(16) uint2 cache[N];
    __shared__ __align__(16) uint2 list[N * K];
    __shared__ unsigned colUsed[N / 32];

    const int lane = threadIdx.x;
    unsigned maskbits = 0;                 // bit k: col (k*64+lane) used
    unsigned long long ptrbits;

    if (lane < N / 32) colUsed[lane] = 0u;

    if (haveList) {
        const uint4* src = (const uint4*)wsList;
        uint4* dst = (uint4*)list;
        #pragma unroll 4
        for (int it = 0; it < (N * K) / (2 * 64); ++it)   // 64 KB copy-in
            dst[it * 64 + lane] = src[it * 64 + lane];
        #pragma unroll
        for (int s = 0; s < SLOTS; ++s)
            cache[(s << 6) + lane] = list[((s << 6) + lane) * K];
        ptrbits = 0ULL;
    } else {
        // fallback (tiny ws): full scan per row, lists disabled (ptr=8)
        for (int r = 0; r < N; ++r) {
            const float* rp = C + (size_t)r * N;
            float best = -INFINITY; int bc = N;
            #pragma unroll
            for (int k = 0; k < SLOTS; ++k) {
                int c = (k << 6) + lane;
                float v = rp[c];
                if (v > best) { best = v; bc = c; }
            }
            wave_argmax(best, bc);
            if (lane == 0) cache[r] = make_uint2((unsigned)bc, __float_as_uint(best));
        }
        ptrbits = 0x8888888888888888ULL;
    }
    __syncthreads();

    const int laneBase = lane << 10;
    #pragma unroll 1
    for (int iter = 0; iter < N; ++iter) {
        // ---- read row cache (16 x ds_read_b64) + local argmax tree --------
        uint2 ce[SLOTS];
        #pragma unroll
        for (int s = 0; s < SLOTS; ++s) ce[s] = cache[(s << 6) + lane];
        float tv[SLOTS]; int tf_[SLOTS];
        #pragma unroll
        for (int s = 0; s < SLOTS; ++s) {
            tv[s]  = __uint_as_float(ce[s].y);
            tf_[s] = (s << 16) | laneBase | (int)(ce[s].x & (N - 1));  // r<<10 | c
        }
        #pragma unroll
        for (int st = 1; st < SLOTS; st <<= 1) {
            #pragma unroll
            for (int s = 0; s < SLOTS; s += (st << 1)) {
                if (better(tv[s + st], tf_[s + st], tv[s], tf_[s])) {
                    tv[s] = tv[s + st]; tf_[s] = tf_[s + st];
                }
            }
        }
        float v = tv[0]; int f = tf_[0];
        wave_argmax(v, f);
        const int br = f >> 10;
        const int bc = f & (N - 1);

        // ---- retire winner row, mark column --------------------------------
        if (lane == 0) {
            cache[br] = make_uint2(0xFFFFFFFFu, 0xFF800000u);  // col=-1, -inf
            colUsed[bc >> 5] |= 1u << (bc & 31);
            out[N + br] = bc;
        }
        if (lane == (bc & 63)) maskbits |= 1u << (bc >> 6);

        // ---- rows whose cached best column just died -----------------------
        unsigned pend = 0;
        #pragma unroll
        for (int s = 0; s < SLOTS; ++s)
            if ((int)ce[s].x == bc) pend |= 1u << s;
        if (lane == (br & 63)) pend &= ~(1u << (br >> 6));   // winner handled

        // ---- pop next unused list entry (per-lane, divergent) --------------
        unsigned resc = 0;
        while (__any(pend != 0)) {
            bool active = pend != 0;
            int s = __ffs(pend) - 1;
            pend &= pend - 1;
            if (active) {
                int r = (s << 6) + lane;
                int j = (int)((ptrbits >> (s << 2)) & 15ULL) + 1;
                bool got = false;
                unsigned nc = 0; unsigned nvb = 0;
                while (j < K) {
                    uint2 e = list[r * K + j];
                    if (!((colUsed[e.x >> 5] >> (e.x & 31)) & 1u)) {
                        nc = e.x; nvb = e.y; got = true; break;
                    }
                    ++j;
                }
                if (j > K) j = K;   // keep nibble in range
                ptrbits = (ptrbits & ~(15ULL << (s << 2)))
                        | ((unsigned long long)j << (s << 2));
                if (got) cache[r] = make_uint2(nc, nvb);
                else     resc |= 1u << s;
            }
        }

        // ---- exhausted lists: wave-cooperative full rescan (rare) ----------
        unsigned long long anyR = __ballot(resc != 0);
        while (anyR) {
            int srclane = __ffsll(anyR) - 1;
            anyR &= anyR - 1;
            unsigned rb = (unsigned)__builtin_amdgcn_readlane((int)resc, srclane);
            while (rb) {
                int s = __ffs(rb) - 1; rb &= rb - 1;
                int r = (s << 6) + srclane;
                const float* rp = C + (size_t)r * N;
                float best = -INFINITY; int bcc = N;
                #pragma unroll
                for (int k = 0; k < SLOTS; ++k) {
                    int c = (k << 6) + lane;
                    float val = rp[c];
                    bool used = (maskbits >> k) & 1u;
                    if (!used && val > best) { best = val; bcc = c; }
                }
                wave_argmax(best, bcc);
                if (lane == 0) cache[r] = make_uint2((unsigned)bcc, __float_as_uint(best));
            }
        }
    }

    // ---- row-index half of the output: identity ---------------------------
    #pragma unroll
    for (int s = 0; s < SLOTS; ++s) out[(s << 6) + lane] = (s << 6) + lane;
}

// ---------------------------------------------------------------------------
extern "C" void kernel_launch(void* const* d_in, const int* in_sizes, int n_in,
                              void* d_out, int out_size, void* d_ws, size_t ws_size,
                              hipStream_t stream) {
    const float* C = (const float*)d_in[0];
    int* out = (int*)d_out;

    if (ws_size >= (size_t)(N * K * sizeof(uint2))) {
        uint2* lists = (uint2*)d_ws;
        init_topk<<<256, 256, 0, stream>>>(C, lists);
        greedy_wave<<<1, 64, 0, stream>>>(C, lists, out, 1);
    } else {
        greedy_wave<<<1, 64, 0, stream>>>(C, nullptr, out, 0);
    }
}